// Round 1
// 59.804 us; speedup vs baseline: 1.0440x; 1.0440x over previous
//
#include <hip/hip_runtime.h>
#include <math.h>

// NDFT type-2, separable 2D: B=2, M=8192, D=2, N=64x64 (K=4096).
// y[b,m] = sum_{k1,k2} f_hat[b,k1,k2] * exp(-2pi*i*((k1-32)*x1 + (k2-32)*x2))
//
// Inner k2 sum now via GOERTZEL (f_hat is REAL -> all-real recurrence):
//   u_n = f_n + 2*cos(2pi*x2)*u_{n+1} - u_{n+2},   u_64 = u_65 = 0
//   S   = sum_k2 f[k2]*w2^k2 = u_0 - conj(w2)*u_1,  w2 = e^{-2pi*i*x2}
// Cost: 2 VALU insts/step (sub + fma) vs 4 for complex Horner; critical path
// 1 FMA (4 cyc)/step vs 2 (8 cyc). Two k1 rows run as independent interleaved
// chains per thread for ILP.
//
// Outer k1: y += P*S, with P(k1) = e^{-2pi*i*(k1-32)*x1} * e^{+2pi*i*32*x2}
//   initialized by ONE combined-angle sincosf, stepped by rotation e^{-2pi*i*x1}.
// 3 sincosf total per thread.
//
// Output layout (R2-verified): planar — out[0:16384]=re(y), out[16384:32768]=im(y).
//
// Occupancy: 256 blocks x 512 threads = 2048 waves = 2 waves/SIMD.

#define TWO_PI 6.28318530717958647692f
#define BM 16384   // B*M

__global__ __launch_bounds__(512) void ndft_kernel(
    const float* __restrict__ x,      // [B, M, 2]
    const float* __restrict__ f_hat,  // [B, 64, 64]
    float* __restrict__ out,
    int planar)
{
    __shared__ float fh[64 * 64];       // 16 KB: f_hat for this block's batch
    __shared__ float part[8][64][2];    // 4 KB: cross-wave partial sums

    const int t   = threadIdx.x;
    const int sub = t >> 6;   // wave id 0..7 -> k1 chunk of 8 (wave-uniform)
    const int lp  = t & 63;   // local point 0..63
    const int gp  = blockIdx.x * 64 + lp;   // global point in [0, 16384)
    const int b   = gp >> 13;               // 64 | 8192 -> uniform per block

    // Stage f_hat[b] (4096 floats = 1024 float4) into LDS: 2 per thread.
    {
        const float4* src = (const float4*)(f_hat + b * 4096);
        float4* dst = (float4*)fh;
        dst[t]       = src[t];
        dst[t + 512] = src[t + 512];
    }
    __syncthreads();

    const float2 xp = ((const float2*)x)[gp];
    const float x1 = xp.x, x2 = xp.y;

    // w2 = e^{-2pi*i*x2} = (c2, -s2); Goertzel coefficient 2*Re(w2) = 2*c2
    float s2, c2;
    sincosf(TWO_PI * x2, &s2, &c2);
    const float twoc = 2.0f * c2;

    // k1 rotation step e^{-2pi*i*x1}: multiplier (c1, -s1)
    float s1, c1;
    sincosf(TWO_PI * x1, &s1, &c1);

    const int k1base = sub << 3;
    // P init at k1 = k1base: angle = -2pi*(k1base-32)*x1 + 2pi*32*x2
    float Pr, Pi;
    {
        const float theta = fmaf(-TWO_PI * (float)(k1base - 32), x1,
                                 (32.0f * TWO_PI) * x2);
        sincosf(theta, &Pi, &Pr);
    }

    float yr = 0.0f, yi = 0.0f;

    // 4 pair-iterations; each runs TWO independent Goertzel chains (k1, k1+1).
    for (int pr2 = 0; pr2 < 4; ++pr2) {
        const int k1 = k1base + (pr2 << 1);
        const float4* f0 = (const float4*)(fh + (k1 << 6));        // wave-uniform
        const float4* f1 = (const float4*)(fh + ((k1 + 1) << 6));  // broadcast

        // Goertzel states: u1* = u_{n+1}, u2* = u_{n+2}
        float u1a = 0.0f, u2a = 0.0f;
        float u1b = 0.0f, u2b = 0.0f;

        #pragma unroll
        for (int q = 15; q >= 0; --q) {
            const float4 fa = f0[q];
            const float4 fb = f1[q];
            // chain a: n = 4q+3, 4q+2, 4q+1, 4q
            {
                const float A = fmaf(twoc, u1a, fa.w - u2a);
                const float B = fmaf(twoc, A,   fa.z - u1a);
                const float C = fmaf(twoc, B,   fa.y - A);
                const float D = fmaf(twoc, C,   fa.x - B);
                u2a = C; u1a = D;
            }
            // chain b (independent -> fills chain-a latency)
            {
                const float A = fmaf(twoc, u1b, fb.w - u2b);
                const float B = fmaf(twoc, A,   fb.z - u1b);
                const float C = fmaf(twoc, B,   fb.y - A);
                const float D = fmaf(twoc, C,   fb.x - B);
                u2b = C; u1b = D;
            }
        }

        // S = u_0 - conj(w2)*u_1, conj(w2) = (c2, +s2); u1*=u_0, u2*=u_1
        const float Sra = fmaf(-c2, u2a, u1a);
        const float Sia = -s2 * u2a;
        const float Srb = fmaf(-c2, u2b, u1b);
        const float Sib = -s2 * u2b;

        // y += P * S_a ; P *= e^{-2pi*i*x1}
        yr = fmaf(Pr, Sra, fmaf(-Pi, Sia, yr));
        yi = fmaf(Pr, Sia, fmaf( Pi, Sra, yi));
        {
            const float nPr = fmaf(Pr, c1,  Pi * s1);
            const float nPi = fmaf(Pi, c1, -Pr * s1);
            Pr = nPr; Pi = nPi;
        }
        // y += P * S_b ; P *= e^{-2pi*i*x1}
        yr = fmaf(Pr, Srb, fmaf(-Pi, Sib, yr));
        yi = fmaf(Pr, Sib, fmaf( Pi, Srb, yi));
        {
            const float nPr = fmaf(Pr, c1,  Pi * s1);
            const float nPi = fmaf(Pi, c1, -Pr * s1);
            Pr = nPr; Pi = nPi;
        }
    }

    part[sub][lp][0] = yr;
    part[sub][lp][1] = yi;
    __syncthreads();

    // Reduce 8 wave-partials; threads 0..127 cover 64 points x {re,im}.
    if (t < 128) {
        const int p = t >> 1, comp = t & 1;
        float s = 0.0f;
        #pragma unroll
        for (int w = 0; w < 8; ++w) s += part[w][p][comp];
        const int g = blockIdx.x * 64 + p;
        if (planar) {
            out[comp * BM + g] = s;        // [re plane | im plane]
        } else if (comp == 0) {
            out[g] = s;
        }
    }
}

extern "C" void kernel_launch(void* const* d_in, const int* in_sizes, int n_in,
                              void* d_out, int out_size, void* d_ws, size_t ws_size,
                              hipStream_t stream) {
    const float* x     = (const float*)d_in[0];   // [2, 8192, 2]
    const float* f_hat = (const float*)d_in[1];   // [2, 64, 64]
    float* out = (float*)d_out;

    const int planar = (out_size >= 2 * BM) ? 1 : 0;

    ndft_kernel<<<dim3(256), dim3(512), 0, stream>>>(x, f_hat, out, planar);
}

// Round 2
// 58.621 us; speedup vs baseline: 1.0651x; 1.0202x over previous
//
#include <hip/hip_runtime.h>
#include <math.h>

// NDFT type-2, separable 2D: B=2, M=8192, D=2, N=64x64 (K=4096).
// y[b,m] = sum_{k1,k2} f_hat[b,k1,k2] * exp(-2pi*i*((k1-32)*x1 + (k2-32)*x2))
//
// R2 change: occupancy 2 -> 8 waves/SIMD. 512 blocks x 1024 threads; each
// thread owns 1 point x 2 k1 rows (two interleaved real Goertzel chains over
// k2). Per-thread state ~40 VGPRs; __launch_bounds__(1024, 8) caps at 64 so
// 2 blocks/CU x 16 waves = 32 waves/CU (HW max).
//
// Goertzel (f_hat REAL -> all-real recurrence):
//   u_n = f_n + 2*cos(2pi*x2)*u_{n+1} - u_{n+2},  S = u_0 - conj(w2)*u_1
// 2 VALU insts per (k2,row), critical path 1 FMA/step.
//
// sin/cos via raw v_sin_f32/v_cos_f32 (HW takes REVOLUTIONS: D=sin(2pi*S0)).
// All our angles are naturally revolutions; |u|<=32 so fract() is exact range
// reduction. Replaces 3 libm sincosf calls (~150 insts) with ~10 insts.
//
// Wave layout: 64 lanes = 32 points x 2 chunks -> each ds_read is a 2-address
// broadcast (free per m136). LDS: 16KB f_hat + 8KB partials = 24KB; 2
// blocks/CU = 48KB < 160KB.
//
// Output layout (R2-verified): planar — out[0:16384]=re(y), out[16384:32768]=im(y).

#define BM 16384   // B*M

__global__ __launch_bounds__(1024, 8) void ndft_kernel(
    const float* __restrict__ x,      // [B, M, 2]
    const float* __restrict__ f_hat,  // [B, 64, 64]
    float* __restrict__ out,
    int planar)
{
    __shared__ float fh[64 * 64];       // 16 KB: f_hat for this block's batch
    __shared__ float part[32][32][2];   // 8 KB: per-chunk partial sums

    const int t     = threadIdx.x;
    const int lane  = t & 63;
    const int wv    = t >> 6;            // wave 0..15
    const int pt    = lane & 31;         // point within block
    const int half  = lane >> 5;         // 0/1
    const int chunk = (wv << 1) | half;  // 0..31 -> k1 pair
    const int k1a   = chunk << 1;        // rows k1a, k1a+1

    const int gp = blockIdx.x * 32 + pt;   // global point in [0, 16384)
    const int b  = gp >> 13;               // 32 | 8192 -> uniform per block

    // Stage f_hat[b] (4096 floats = 1024 float4): one float4 per thread.
    {
        const float4* src = (const float4*)(f_hat + b * 4096);
        ((float4*)fh)[t] = src[t];
    }
    __syncthreads();

    const float2 xp = ((const float2*)x)[gp];
    const float x1 = xp.x, x2 = xp.y;

    // w2 = e^{-2pi*i*x2} = (c2, -s2); Goertzel coefficient 2*c2.
    const float u2r = x2 - floorf(x2);               // exact fract
    const float s2  = __builtin_amdgcn_sinf(u2r);    // sin(2pi*u)
    const float c2  = __builtin_amdgcn_cosf(u2r);
    const float twoc = 2.0f * c2;

    // k1 rotation e^{-2pi*i*x1} = (c1, -s1)
    const float u1r = x1 - floorf(x1);
    const float s1  = __builtin_amdgcn_sinf(u1r);
    const float c1  = __builtin_amdgcn_cosf(u1r);

    // P(k1a) = e^{i*2pi*((32-k1a)*x1 + 32*x2)}; |u| <= 32 so fract exact.
    float uP = (float)(32 - k1a) * x1 + 32.0f * x2;
    uP -= floorf(uP);
    const float Pi_ = __builtin_amdgcn_sinf(uP);
    const float Pr_ = __builtin_amdgcn_cosf(uP);

    // Two independent Goertzel chains (rows k1a, k1a+1).
    const float4* f0 = (const float4*)(fh + (k1a << 6));        // 2-addr bcast
    const float4* f1 = (const float4*)(fh + ((k1a + 1) << 6));

    float u1a = 0.0f, u2a = 0.0f;
    float u1b = 0.0f, u2b = 0.0f;

    #pragma unroll
    for (int q = 15; q >= 0; --q) {
        const float4 fa = f0[q];
        const float4 fb = f1[q];
        {   // chain a: n = 4q+3 .. 4q
            const float A = fmaf(twoc, u1a, fa.w - u2a);
            const float B = fmaf(twoc, A,   fa.z - u1a);
            const float C = fmaf(twoc, B,   fa.y - A);
            const float D = fmaf(twoc, C,   fa.x - B);
            u2a = C; u1a = D;
        }
        {   // chain b (independent -> fills chain-a latency)
            const float A = fmaf(twoc, u1b, fb.w - u2b);
            const float B = fmaf(twoc, A,   fb.z - u1b);
            const float C = fmaf(twoc, B,   fb.y - A);
            const float D = fmaf(twoc, C,   fb.x - B);
            u2b = C; u1b = D;
        }
    }

    // S = u_0 - conj(w2)*u_1, conj(w2) = (c2, +s2)
    const float Sra = fmaf(-c2, u2a, u1a);
    const float Sia = -s2 * u2a;
    const float Srb = fmaf(-c2, u2b, u1b);
    const float Sib = -s2 * u2b;

    // Pb = P * (c1, -s1)
    const float Pbr = fmaf(Pr_, c1,  Pi_ * s1);
    const float Pbi = fmaf(Pi_, c1, -Pr_ * s1);

    // y = P*Sa + Pb*Sb
    float yr, yi;
    yr = fmaf(Pr_, Sra, -Pi_ * Sia);
    yi = fmaf(Pr_, Sia,  Pi_ * Sra);
    yr = fmaf(Pbr, Srb, fmaf(-Pbi, Sib, yr));
    yi = fmaf(Pbr, Sib, fmaf( Pbi, Srb, yi));

    part[chunk][pt][0] = yr;
    part[chunk][pt][1] = yi;
    __syncthreads();

    // Reduce 32 chunk-partials; threads 0..63 cover 32 points x {re,im}.
    // Read addresses are linear in t per w-step -> conflict-free.
    if (t < 64) {
        const int p = t >> 1, comp = t & 1;
        float s = 0.0f;
        #pragma unroll
        for (int w = 0; w < 32; ++w) s += part[w][p][comp];
        const int g = blockIdx.x * 32 + p;
        if (planar) {
            out[comp * BM + g] = s;        // [re plane | im plane]
        } else if (comp == 0) {
            out[g] = s;
        }
    }
}

extern "C" void kernel_launch(void* const* d_in, const int* in_sizes, int n_in,
                              void* d_out, int out_size, void* d_ws, size_t ws_size,
                              hipStream_t stream) {
    const float* x     = (const float*)d_in[0];   // [2, 8192, 2]
    const float* f_hat = (const float*)d_in[1];   // [2, 64, 64]
    float* out = (float*)d_out;

    const int planar = (out_size >= 2 * BM) ? 1 : 0;

    ndft_kernel<<<dim3(512), dim3(1024), 0, stream>>>(x, f_hat, out, planar);
}